// Round 15
// baseline (281.652 us; speedup 1.0000x reference)
//
#include <hip/hip_runtime.h>
#include <hip/hip_bf16.h>

#define BM 128
#define BN 128
#define BK 32
#define TB 512
#define LDK 40   // padded LDS row stride (80 B): b128 frag reads conflict-free
#define KSTEPS 16

typedef __attribute__((ext_vector_type(8))) short bf16x8;
typedef __attribute__((ext_vector_type(4))) float f32x4;
typedef __attribute__((ext_vector_type(4))) int   i32x4;

static __device__ inline int pk2(float a, float b) {
    // two fp32 -> packed bf16 (RNE)
    __hip_bfloat162 h = __float22bfloat162_rn(float2{a, b});
    int r;
    __builtin_memcpy(&r, &h, 4);
    return r;
}

// R14 structure (8 waves, VGPR 40, occ 55%, 120.5us) + ONE unit of change:
// depth-2 register prefetch with an lgkmcnt-only barrier so tile ks+2's
// global loads stay in flight ACROSS the barrier. R14 proved TLP alone
// doesn't help (occ 2x, dur unchanged): every wave drains vmcnt(0) at the
// same __syncthreads each step (~4500cy/step vs ~1000 of work). This keeps
// ~64B/thread continuously in flight (~73KB/CU >> ~10KB needed for 6.3TB/s).
// R3 proved the lgkm-only barrier correct; it failed perf-wise only because
// the 4-wave base (VGPR 84->116) collapsed occupancy - at VGPR-40 base the
// depth-2 cost (~+32) leaves occupancy untouched.
__global__ __launch_bounds__(TB) void bgemm_bt_bias(
    const float* __restrict__ X,     // [8, 8192, 512]
    const float* __restrict__ Wt,    // [8, 512, 512]
    const float* __restrict__ Bias,  // [8, 512]
    float* __restrict__ Out)         // [8, 8192, 512]
{
    // XCD-aware swizzle: 4 n-tiles sharing an x-panel land on one XCD
    const int flat  = blockIdx.x;          // 0..2047
    const int xcd   = flat & 7;
    const int rr    = flat >> 3;
    const int nt    = rr & 3;
    const int p     = rr >> 2;
    const int panel = p * 8 + xcd;
    const int mt    = panel & 63;
    const int b     = panel >> 6;

    const int m0  = mt * BM;
    const int n0  = nt * BN;
    const int tid = threadIdx.x;
    const int lane = tid & 63;
    const int wave = tid >> 6;             // 0..7
    const int wm = (wave >> 2) * 64;       // 2 m-groups {0,64}
    const int wn = (wave & 3) * 32;        // 4 n-groups {0,32,64,96}

    __shared__ short As[2][BM * LDK];
    __shared__ short Bs[2][BN * LDK];

    // slab-coalesced staging: thread t -> row t>>2, 8 floats at col (t&3)*8
    const int lrow = tid >> 2;         // 0..127
    const int lcol = (tid & 3) * 8;    // float col within the 32-float K chunk

    const float* xg = X  + ((size_t)b * 8192 + m0 + lrow) * 512 + lcol;
    const float* wg = Wt + ((size_t)b * 512  + n0 + lrow) * 512 + lcol;

    // two named prefetch sets (static names: stay in registers, rule #20)
    f32x4 xl0, xh0, wl0, wh0;
    f32x4 xl1, xh1, wl1, wh1;

#define LOADT(S, t) do {                                                        \
    xl##S = *(const f32x4*)(xg + (t) * BK);                                     \
    xh##S = *(const f32x4*)(xg + (t) * BK + 4);                                 \
    wl##S = *(const f32x4*)(wg + (t) * BK);                                     \
    wh##S = *(const f32x4*)(wg + (t) * BK + 4);                                 \
} while (0)

#define STORET(S, buf) do {                                                     \
    i32x4 pa;                                                                   \
    pa[0] = pk2(xl##S[0], xl##S[1]); pa[1] = pk2(xl##S[2], xl##S[3]);           \
    pa[2] = pk2(xh##S[0], xh##S[1]); pa[3] = pk2(xh##S[2], xh##S[3]);           \
    *(i32x4*)&As[buf][lrow * LDK + lcol] = pa;                                  \
    i32x4 pb;                                                                   \
    pb[0] = pk2(wl##S[0], wl##S[1]); pb[1] = pk2(wl##S[2], wl##S[3]);           \
    pb[2] = pk2(wh##S[0], wh##S[1]); pb[3] = pk2(wh##S[2], wh##S[3]);           \
    *(i32x4*)&Bs[buf][lrow * LDK + lcol] = pb;                                  \
} while (0)

// lgkm-only barrier (R3-proven correct): LDS ordering needs lgkmcnt(0) only;
// register-destined global loads legally stay outstanding across s_barrier.
// sched_barrier stops next-step ds_reads hoisting above the barrier.
#define BARRIER() do {                                                          \
    asm volatile("s_waitcnt lgkmcnt(0)" ::: "memory");                          \
    __builtin_amdgcn_s_barrier();                                               \
    __builtin_amdgcn_sched_barrier(0);                                          \
} while (0)

    // One K-step: issue tile ks+2 into set SI; compute buf C (tile ks);
    // convert+write set SC (tile ks+1) into buf C^1 — compiler's auto waitcnt
    // on SC's registers is vmcnt(4): SI's 4 loads stay in flight over BARRIER.
#define STEPK(ks, C, SI, SC) do {                                               \
    if ((ks) + 2 < KSTEPS) LOADT(SI, (ks) + 2);                                 \
    bf16x8 af[4], bfr[2];                                                       \
    _Pragma("unroll")                                                           \
    for (int mf = 0; mf < 4; ++mf)                                              \
        af[mf] = *(const bf16x8*)&As[C][(wm + mf * 16 + frow) * LDK + fk];      \
    _Pragma("unroll")                                                           \
    for (int nf = 0; nf < 2; ++nf)                                              \
        bfr[nf] = *(const bf16x8*)&Bs[C][(wn + nf * 16 + frow) * LDK + fk];     \
    _Pragma("unroll")                                                           \
    for (int mf = 0; mf < 4; ++mf)                                              \
        _Pragma("unroll")                                                       \
        for (int nf = 0; nf < 2; ++nf)                                          \
            acc[mf][nf] = __builtin_amdgcn_mfma_f32_16x16x32_bf16(              \
                af[mf], bfr[nf], acc[mf][nf], 0, 0, 0);                         \
    if ((ks) + 1 < KSTEPS) STORET(SC, (C) ^ 1);                                 \
    BARRIER();                                                                  \
} while (0)

    // ---- prologue: tile0 -> buf0; tile1 loads in flight across the barrier ----
    LOADT(0, 0);
    LOADT(1, 1);
    STORET(0, 0);          // waits vmcnt(4): only set0 drained
    BARRIER();

    f32x4 acc[4][2];
#pragma unroll
    for (int i = 0; i < 4; ++i)
#pragma unroll
        for (int j = 0; j < 2; ++j)
            acc[i][j] = (f32x4){0.f, 0.f, 0.f, 0.f};

    const int frow = lane & 15;
    const int fk   = (lane >> 4) * 8;

    // set0 holds even tiles, set1 odd; buf = tile&1
    for (int ks = 0; ks < KSTEPS; ks += 2) {
        STEPK(ks,     0, 0, 1);   // compute tile ks   (buf0); issue ks+2->set0; write tile ks+1 (set1)->buf1
        STEPK(ks + 1, 1, 1, 0);   // compute tile ks+1 (buf1); issue ks+3->set1; write tile ks+2 (set0)->buf0
    }
#undef STEPK
#undef BARRIER
#undef STORET
#undef LOADT

    // ---- epilogue: add bias, store fp32 ----
    float bv[2];
    const float* biasp = Bias + (size_t)b * 512 + n0 + wn;
#pragma unroll
    for (int nf = 0; nf < 2; ++nf)
        bv[nf] = biasp[nf * 16 + frow];

    float* outp = Out + ((size_t)b * 8192 + m0 + wm) * 512 + n0 + wn;
    const int orow = (lane >> 4) * 4;   // C/D: row = (lane>>4)*4 + reg
#pragma unroll
    for (int mf = 0; mf < 4; ++mf)
#pragma unroll
        for (int nf = 0; nf < 2; ++nf)
#pragma unroll
            for (int r = 0; r < 4; ++r)
                outp[(size_t)(mf * 16 + orow + r) * 512 + nf * 16 + frow] =
                    acc[mf][nf][r] + bv[nf];
}

extern "C" void kernel_launch(void* const* d_in, const int* in_sizes, int n_in,
                              void* d_out, int out_size, void* d_ws, size_t ws_size,
                              hipStream_t stream) {
    const float* X    = (const float*)d_in[0];
    const float* Wt   = (const float*)d_in[1];
    const float* Bias = (const float*)d_in[2];
    float* Out        = (float*)d_out;

    dim3 grid(2048);
    bgemm_bt_bias<<<grid, TB, 0, stream>>>(X, Wt, Bias, Out);
}